// Round 1
// baseline (3800.566 us; speedup 1.0000x reference)
//
#include <hip/hip_runtime.h>
#include <math.h>

#define DEV static __device__ __forceinline__

// ---- ordered-uint encoding for float atomic max ----
DEV unsigned fenc(float f) {
    unsigned u = __float_as_uint(f);
    return (u & 0x80000000u) ? ~u : (u | 0x80000000u);
}
DEV float fdec(unsigned u) {
    return __uint_as_float((u & 0x80000000u) ? (u ^ 0x80000000u) : ~u);
}
DEV void atomic_max_u32(unsigned* p, unsigned v) {
    __hip_atomic_fetch_max(p, v, __ATOMIC_RELAXED, __HIP_MEMORY_SCOPE_AGENT);
}
DEV void atomic_add_f32(float* p, float v) {
    __hip_atomic_fetch_add(p, v, __ATOMIC_RELAXED, __HIP_MEMORY_SCOPE_AGENT);
}

// ---- node projection: xp = in @ W.T, K input channels, 80 outputs ----
template<int K>
__global__ void k_proj(const float* __restrict__ in, const float* __restrict__ W,
                       float* __restrict__ xp, int N) {
    int i = blockIdx.x * blockDim.x + threadIdx.x;   // n*80 + oc
    if (i >= N * 80) return;
    int n = i / 80, oc = i % 80;
    const float* xr = in + (size_t)n * K;
    const float* wr = W + (size_t)oc * K;
    float s = 0.f;
    #pragma unroll
    for (int j = 0; j < K; ++j) s += xr[j] * wr[j];
    xp[i] = s;
}

// ---- per-(node,head) attention terms ----
__global__ void k_terms(const float* __restrict__ xp,
                        const float* __restrict__ a_s, const float* __restrict__ a_d,
                        float* __restrict__ sterm, float* __restrict__ dterm, int N) {
    int i = blockIdx.x * blockDim.x + threadIdx.x;   // n*16 + h
    if (i >= N * 16) return;
    int n = i / 16, h = i % 16;
    const float* xr = xp + (size_t)n * 80 + h * 5;
    float ss = 0.f, sd = 0.f;
    #pragma unroll
    for (int c = 0; c < 5; ++c) { ss += xr[c] * a_s[h * 5 + c]; sd += xr[c] * a_d[h * 5 + c]; }
    sterm[i] = ss; dterm[i] = sd;
}

// ---- q[h] = sum_c We[h*5+c, 0/1] * a_e[h,c]  (edge-attr folding) ----
__global__ void k_q(const float* __restrict__ We, const float* __restrict__ a_e,
                    float* __restrict__ q) {
    int h = threadIdx.x;
    if (h >= 16) return;
    float q0 = 0.f, q1 = 0.f;
    #pragma unroll
    for (int c = 0; c < 5; ++c) {
        q0 += We[(h * 5 + c) * 2 + 0] * a_e[h * 5 + c];
        q1 += We[(h * 5 + c) * 2 + 1] * a_e[h * 5 + c];
    }
    q[h] = q0; q[16 + h] = q1;
}

DEV float edge_logit(int s, int d, float ea0, float ea1, int h,
                     const float* __restrict__ sterm, const float* __restrict__ dterm,
                     const float* __restrict__ q) {
    float al = sterm[s * 16 + h] + dterm[d * 16 + h] + ea0 * q[h] + ea1 * q[16 + h];
    return al >= 0.f ? al : 0.2f * al;
}

template<bool MASKED>
__global__ void k_edge_max(const int* __restrict__ src, const int* __restrict__ dst,
                           const float* __restrict__ ea,
                           const float* __restrict__ sterm, const float* __restrict__ dterm,
                           const float* __restrict__ q, unsigned* __restrict__ mbuf,
                           int E, int Etot) {
    int t = blockIdx.x * blockDim.x + threadIdx.x;
    if (t >= Etot * 16) return;
    int e = t >> 4, h = t & 15;
    int s, d; float ea0, ea1;
    if (e < E) {
        s = src[e]; d = dst[e]; ea0 = ea[2 * e]; ea1 = ea[2 * e + 1];
        if (MASKED && !(ea0 > 1.0f)) return;   // masked edge == removed edge
    } else { s = d = e - E; ea0 = ea1 = 0.f; }
    float al = edge_logit(s, d, ea0, ea1, h, sterm, dterm, q);
    atomic_max_u32(&mbuf[d * 16 + h], fenc(al));
}

template<bool MASKED>
__global__ void k_edge_accum(const int* __restrict__ src, const int* __restrict__ dst,
                             const float* __restrict__ ea,
                             const float* __restrict__ sterm, const float* __restrict__ dterm,
                             const float* __restrict__ q, const unsigned* __restrict__ mbuf,
                             const float* __restrict__ xp,
                             float* __restrict__ denom, float* __restrict__ num,
                             int E, int Etot) {
    int t = blockIdx.x * blockDim.x + threadIdx.x;
    if (t >= Etot * 16) return;
    int e = t >> 4, h = t & 15;
    int s, d; float ea0, ea1;
    if (e < E) {
        s = src[e]; d = dst[e]; ea0 = ea[2 * e]; ea1 = ea[2 * e + 1];
        if (MASKED && !(ea0 > 1.0f)) return;
    } else { s = d = e - E; ea0 = ea1 = 0.f; }
    float al = edge_logit(s, d, ea0, ea1, h, sterm, dterm, q);
    float w = expf(al - fdec(mbuf[d * 16 + h]));   // al <= m, so w <= 1
    atomic_add_f32(&denom[d * 16 + h], w);
    const float* xr = xp + (size_t)s * 80 + h * 5;
    float* nr = num + (size_t)d * 80 + h * 5;
    #pragma unroll
    for (int c = 0; c < 5; ++c) atomic_add_f32(&nr[c], w * xr[c]);
}

// ---- h_out = num/denom + b  (in-place on num) ----
__global__ void k_finalize(float* __restrict__ num, const float* __restrict__ denom,
                           const float* __restrict__ b, int N) {
    int i = blockIdx.x * blockDim.x + threadIdx.x;   // n*80 + hc
    if (i >= N * 80) return;
    int n = i / 80, hc = i % 80;
    num[i] = num[i] / denom[n * 16 + hc / 5] + b[hc];
}

// ---- scatter-max pool by timing bin ----
__global__ void k_pool(const float* __restrict__ x, const float* __restrict__ h2,
                       unsigned* __restrict__ pool, int N) {
    int i = blockIdx.x * blockDim.x + threadIdx.x;   // n*80 + ch
    if (i >= N * 80) return;
    int n = i / 80, ch = i % 80;
    int t = (int)x[(size_t)n * 5 + 2];               // timing bin, 0..499
    atomic_max_u32(&pool[t * 80 + ch], fenc(h2[i]));
}

__global__ void k_pool_dec(unsigned* __restrict__ pool, int total) {
    int i = blockIdx.x * blockDim.x + threadIdx.x;
    if (i >= total) return;
    unsigned u = pool[i];
    float f = (u == 0u) ? 0.f : fdec(u);             // empty segment -> 0 (isfinite clause)
    ((float*)pool)[i] = f;
}

// ---- strided conv1d, k=10, stride=2, pad=1, + leaky 0.01 ----
__global__ void k_conv(const float* __restrict__ in, const float* __restrict__ w,
                       const float* __restrict__ b, float* __restrict__ out,
                       int Bn, int IC, int Lin, int OC, int Lout) {
    int i = blockIdx.x * blockDim.x + threadIdx.x;   // g*OC*Lout + oc*Lout + t
    if (i >= Bn * OC * Lout) return;
    int t = i % Lout, oc = (i / Lout) % OC, g = i / (OC * Lout);
    float s = b[oc];
    for (int ic = 0; ic < IC; ++ic) {
        const float* ir = in + (size_t)g * IC * Lin + (size_t)ic * Lin;
        const float* wr = w + (size_t)oc * IC * 10 + ic * 10;
        #pragma unroll
        for (int k = 0; k < 10; ++k) {
            int p = 2 * t + k - 1;
            if (p >= 0 && p < Lin) s += ir[p] * wr[k];
        }
    }
    out[i] = s >= 0.f ? s : 0.01f * s;
}

// ---- maxpool1d(k=10,s=10) over L=57 -> 5, flatten to [B,80] ----
__global__ void k_maxpool(const float* __restrict__ c3, float* __restrict__ zf, int Bn) {
    int i = blockIdx.x * blockDim.x + threadIdx.x;   // g*80 + ch*5 + w
    if (i >= Bn * 80) return;
    int g = i / 80, r = i % 80, ch = r / 5, wd = r % 5;
    const float* p = c3 + (size_t)g * 16 * 57 + ch * 57 + wd * 10;
    float m = p[0];
    #pragma unroll
    for (int k = 1; k < 10; ++k) m = fmaxf(m, p[k]);
    zf[i] = m;
}

// ---- 80->128->128->1 MLP, leaky 0.01, optional tanh; one block per graph ----
__global__ void k_mlp(const float* __restrict__ zf,
                      const float* __restrict__ w1, const float* __restrict__ b1,
                      const float* __restrict__ w2, const float* __restrict__ b2,
                      const float* __restrict__ w3, const float* __restrict__ b3,
                      float* __restrict__ out, int which) {
    __shared__ float zin[80], h1s[128], h2s[128];
    int g = blockIdx.x, j = threadIdx.x;
    if (j < 80) zin[j] = zf[g * 80 + j];
    __syncthreads();
    float s = b1[j];
    for (int k = 0; k < 80; ++k) s += zin[k] * w1[j * 80 + k];
    h1s[j] = s >= 0.f ? s : 0.01f * s;
    __syncthreads();
    s = b2[j];
    for (int k = 0; k < 128; ++k) s += h1s[k] * w2[j * 128 + k];
    h2s[j] = s >= 0.f ? s : 0.01f * s;
    __syncthreads();
    if (j == 0) {
        float o = b3[0];
        for (int k = 0; k < 128; ++k) o += h2s[k] * w3[k];
        if (which == 0) o = tanhf(o);
        out[g * 3 + which] = o;
    }
}

extern "C" void kernel_launch(void* const* d_in, const int* in_sizes, int n_in,
                              void* d_out, int out_size, void* d_ws, size_t ws_size,
                              hipStream_t stream) {
    const float* x        = (const float*)d_in[0];
    const float* ea       = (const float*)d_in[1];
    const float* g1_W  = (const float*)d_in[2];
    const float* g1_We = (const float*)d_in[3];
    const float* g1_as = (const float*)d_in[4];
    const float* g1_ad = (const float*)d_in[5];
    const float* g1_ae = (const float*)d_in[6];
    const float* g1_b  = (const float*)d_in[7];
    const float* g2_W  = (const float*)d_in[8];
    const float* g2_We = (const float*)d_in[9];
    const float* g2_as = (const float*)d_in[10];
    const float* g2_ad = (const float*)d_in[11];
    const float* g2_ae = (const float*)d_in[12];
    const float* g2_b  = (const float*)d_in[13];
    const float* c1w = (const float*)d_in[14]; const float* c1b = (const float*)d_in[15];
    const float* c2w = (const float*)d_in[16]; const float* c2b = (const float*)d_in[17];
    const float* c3w = (const float*)d_in[18]; const float* c3b = (const float*)d_in[19];
    const int*   eidx = (const int*)d_in[38];
    float* out = (float*)d_out;

    const int N = in_sizes[0] / 5;
    const int E = in_sizes[38] / 2;
    const int Etot = E + N;
    const int B = 64, SIZE = 500;
    const int* src = eidx;
    const int* dst = eidx + E;

    // ---- workspace layout (floats) ----
    float* ws = (float*)d_ws;
    size_t o = 0;
    float*    xp    = ws + o; o += (size_t)N * 80;
    float*    num1  = ws + o; o += (size_t)N * 80;   // becomes h1
    float*    num2  = ws + o; o += (size_t)N * 80;   // becomes h2
    float*    sterm = ws + o; o += (size_t)N * 16;
    float*    dterm = ws + o; o += (size_t)N * 16;
    unsigned* mbuf  = (unsigned*)(ws + o); o += (size_t)N * 16;
    float*    denom = ws + o; o += (size_t)N * 16;
    float*    q     = ws + o; o += 32;
    unsigned* pool  = (unsigned*)(ws + o); o += (size_t)B * SIZE * 80;
    float*    c1    = ws + o; o += (size_t)B * 16 * 247;
    float*    c2    = ws + o; o += (size_t)B * 16 * 120;
    float*    c3    = ws + o; o += (size_t)B * 16 * 57;
    float*    zf    = ws + o; o += (size_t)B * 80;

    const int BS = 256;
    auto blocks = [&](long long n) { return (int)((n + BS - 1) / BS); };

    // ================= GAT layer 1 =================
    hipMemsetAsync(num1,  0, (size_t)N * 80 * 4, stream);
    hipMemsetAsync(mbuf,  0, (size_t)N * 16 * 4, stream);   // 0u == encoded minimum
    hipMemsetAsync(denom, 0, (size_t)N * 16 * 4, stream);
    k_proj<5><<<blocks((long long)N * 80), BS, 0, stream>>>(x, g1_W, xp, N);
    k_terms<<<blocks((long long)N * 16), BS, 0, stream>>>(xp, g1_as, g1_ad, sterm, dterm, N);
    k_q<<<1, 16, 0, stream>>>(g1_We, g1_ae, q);
    k_edge_max<false><<<blocks((long long)Etot * 16), BS, 0, stream>>>(
        src, dst, ea, sterm, dterm, q, mbuf, E, Etot);
    k_edge_accum<false><<<blocks((long long)Etot * 16), BS, 0, stream>>>(
        src, dst, ea, sterm, dterm, q, mbuf, xp, denom, num1, E, Etot);
    k_finalize<<<blocks((long long)N * 80), BS, 0, stream>>>(num1, denom, g1_b, N);

    // ================= GAT layer 2 =================
    hipMemsetAsync(num2,  0, (size_t)N * 80 * 4, stream);
    hipMemsetAsync(mbuf,  0, (size_t)N * 16 * 4, stream);
    hipMemsetAsync(denom, 0, (size_t)N * 16 * 4, stream);
    k_proj<80><<<blocks((long long)N * 80), BS, 0, stream>>>(num1, g2_W, xp, N);
    k_terms<<<blocks((long long)N * 16), BS, 0, stream>>>(xp, g2_as, g2_ad, sterm, dterm, N);
    k_q<<<1, 16, 0, stream>>>(g2_We, g2_ae, q);
    k_edge_max<true><<<blocks((long long)Etot * 16), BS, 0, stream>>>(
        src, dst, ea, sterm, dterm, q, mbuf, E, Etot);
    k_edge_accum<true><<<blocks((long long)Etot * 16), BS, 0, stream>>>(
        src, dst, ea, sterm, dterm, q, mbuf, xp, denom, num2, E, Etot);
    k_finalize<<<blocks((long long)N * 80), BS, 0, stream>>>(num2, denom, g2_b, N);

    // ================= pooling =================
    hipMemsetAsync(pool, 0, (size_t)B * SIZE * 80 * 4, stream);
    k_pool<<<blocks((long long)N * 80), BS, 0, stream>>>(x, num2, pool, N);
    k_pool_dec<<<blocks((long long)B * SIZE * 80), BS, 0, stream>>>(pool, B * SIZE * 80);
    float* poolf = (float*)pool;   // flat [B*500*80]; conv1 reads the reshape view

    // ================= conv tower =================
    k_conv<<<blocks((long long)B * 16 * 247), BS, 0, stream>>>(poolf, c1w, c1b, c1, B, 80, 500, 16, 247);
    k_conv<<<blocks((long long)B * 16 * 120), BS, 0, stream>>>(c1,    c2w, c2b, c2, B, 16, 247, 16, 120);
    k_conv<<<blocks((long long)B * 16 * 57),  BS, 0, stream>>>(c2,    c3w, c3b, c3, B, 16, 120, 16, 57);
    k_maxpool<<<blocks((long long)B * 80), BS, 0, stream>>>(c3, zf, B);

    // ================= heads =================
    k_mlp<<<B, 128, 0, stream>>>(zf, (const float*)d_in[20], (const float*)d_in[21],
                                 (const float*)d_in[22], (const float*)d_in[23],
                                 (const float*)d_in[24], (const float*)d_in[25], out, 0);
    k_mlp<<<B, 128, 0, stream>>>(zf, (const float*)d_in[26], (const float*)d_in[27],
                                 (const float*)d_in[28], (const float*)d_in[29],
                                 (const float*)d_in[30], (const float*)d_in[31], out, 1);
    k_mlp<<<B, 128, 0, stream>>>(zf, (const float*)d_in[32], (const float*)d_in[33],
                                 (const float*)d_in[34], (const float*)d_in[35],
                                 (const float*)d_in[36], (const float*)d_in[37], out, 2);
}

// Round 2
// 1026.274 us; speedup vs baseline: 3.7033x; 3.7033x over previous
//
#include <hip/hip_runtime.h>
#include <math.h>

#define DEV static __device__ __forceinline__

// ---- ordered-uint encoding for float atomic max ----
DEV unsigned fenc(float f) {
    unsigned u = __float_as_uint(f);
    return (u & 0x80000000u) ? ~u : (u | 0x80000000u);
}
DEV float fdec(unsigned u) {
    return __uint_as_float((u & 0x80000000u) ? (u ^ 0x80000000u) : ~u);
}
DEV void atomic_max_u32(unsigned* p, unsigned v) {
    __hip_atomic_fetch_max(p, v, __ATOMIC_RELAXED, __HIP_MEMORY_SCOPE_AGENT);
}

// ---- node projection: xp = in @ W.T, K input channels, 80 outputs ----
template<int K>
__global__ void k_proj(const float* __restrict__ in, const float* __restrict__ W,
                       float* __restrict__ xp, int N) {
    int i = blockIdx.x * blockDim.x + threadIdx.x;   // n*80 + oc
    if (i >= N * 80) return;
    int n = i / 80, oc = i % 80;
    const float* xr = in + (size_t)n * K;
    const float* wr = W + (size_t)oc * K;
    float s = 0.f;
    #pragma unroll
    for (int j = 0; j < K; ++j) s += xr[j] * wr[j];
    xp[i] = s;
}

// ---- per-(node,head) attention terms ----
__global__ void k_terms(const float* __restrict__ xp,
                        const float* __restrict__ a_s, const float* __restrict__ a_d,
                        float* __restrict__ sterm, float* __restrict__ dterm, int N) {
    int i = blockIdx.x * blockDim.x + threadIdx.x;   // n*16 + h
    if (i >= N * 16) return;
    int n = i / 16, h = i % 16;
    const float* xr = xp + (size_t)n * 80 + h * 5;
    float ss = 0.f, sd = 0.f;
    #pragma unroll
    for (int c = 0; c < 5; ++c) { ss += xr[c] * a_s[h * 5 + c]; sd += xr[c] * a_d[h * 5 + c]; }
    sterm[i] = ss; dterm[i] = sd;
}

// ---- q[h] = sum_c We[h*5+c, 0/1] * a_e[h,c]  (edge-attr folding) ----
__global__ void k_q(const float* __restrict__ We, const float* __restrict__ a_e,
                    float* __restrict__ q) {
    int h = threadIdx.x;
    if (h >= 16) return;
    float q0 = 0.f, q1 = 0.f;
    #pragma unroll
    for (int c = 0; c < 5; ++c) {
        q0 += We[(h * 5 + c) * 2 + 0] * a_e[h * 5 + c];
        q1 += We[(h * 5 + c) * 2 + 1] * a_e[h * 5 + c];
    }
    q[h] = q0; q[16 + h] = q1;
}

// ================= CSR build (by dst) =================
__global__ void k_hist(const int* __restrict__ dst, int* __restrict__ deg, int E) {
    int e = blockIdx.x * blockDim.x + threadIdx.x;
    if (e >= E) return;
    __hip_atomic_fetch_add(&deg[dst[e]], 1, __ATOMIC_RELAXED, __HIP_MEMORY_SCOPE_AGENT);
}

#define SCAN_B 256
__global__ void k_bsum(const int* __restrict__ deg, int* __restrict__ bsum, int N) {
    __shared__ int sm[SCAN_B];
    int i = blockIdx.x * SCAN_B + threadIdx.x;
    sm[threadIdx.x] = (i < N) ? deg[i] : 0;
    __syncthreads();
    for (int s = SCAN_B / 2; s > 0; s >>= 1) {
        if (threadIdx.x < s) sm[threadIdx.x] += sm[threadIdx.x + s];
        __syncthreads();
    }
    if (threadIdx.x == 0) bsum[blockIdx.x] = sm[0];
}

// single block of 512 threads; exclusive-scans bsum[0..G), G <= 512
__global__ void k_bscan(int* __restrict__ bsum, int G) {
    __shared__ int sm[512];
    int t = threadIdx.x;
    int orig = (t < G) ? bsum[t] : 0;
    sm[t] = orig;
    __syncthreads();
    for (int s = 1; s < 512; s <<= 1) {
        int v = (t >= s) ? sm[t - s] : 0;
        __syncthreads();
        sm[t] += v;
        __syncthreads();
    }
    if (t < G) bsum[t] = sm[t] - orig;
}

// per-block exclusive scan + block offset -> off[i]; also seeds cursor buffer.
// deg and cur may alias (each thread reads its own slot before writing).
__global__ void k_apply(const int* __restrict__ deg, int* __restrict__ off,
                        int* __restrict__ cur, const int* __restrict__ bsum, int N) {
    __shared__ int sm[SCAN_B];
    int i = blockIdx.x * SCAN_B + threadIdx.x;
    int v = (i < N) ? deg[i] : 0;
    sm[threadIdx.x] = v;
    __syncthreads();
    for (int s = 1; s < SCAN_B; s <<= 1) {
        int t = (threadIdx.x >= s) ? sm[threadIdx.x - s] : 0;
        __syncthreads();
        sm[threadIdx.x] += t;
        __syncthreads();
    }
    if (i < N) {
        int excl = bsum[blockIdx.x] + sm[threadIdx.x] - v;
        off[i] = excl;
        cur[i] = excl;
        if (i == N - 1) off[N] = excl + v;
    }
}

__global__ void k_scatter(const int* __restrict__ src, const int* __restrict__ dst,
                          const float* __restrict__ ea, int* __restrict__ cur,
                          int* __restrict__ esrc, float2* __restrict__ eea, int E) {
    int e = blockIdx.x * blockDim.x + threadIdx.x;
    if (e >= E) return;
    int d = dst[e];
    int p = __hip_atomic_fetch_add(&cur[d], 1, __ATOMIC_RELAXED, __HIP_MEMORY_SCOPE_AGENT);
    esrc[p] = src[e];
    eea[p] = make_float2(ea[2 * e], ea[2 * e + 1]);
}

// ================= fused GAT aggregation =================
// one thread per (dst node, head); two register passes over the CSR segment.
template<bool MASKED>
__global__ void k_gat(const int* __restrict__ off, const int* __restrict__ esrc,
                      const float2* __restrict__ eea,
                      const float* __restrict__ sterm, const float* __restrict__ dterm,
                      const float* __restrict__ q, const float* __restrict__ xp,
                      const float* __restrict__ bias, float* __restrict__ hout, int N) {
    int i = blockIdx.x * blockDim.x + threadIdx.x;   // d*16 + h
    if (i >= N * 16) return;
    int d = i >> 4, h = i & 15;
    float q0 = q[h], q1 = q[16 + h];
    float dt = dterm[i];
    int e0 = off[d], e1 = off[d + 1];

    // self-loop logit (ea = 0)
    float sl = sterm[i] + dt;
    sl = sl >= 0.f ? sl : 0.2f * sl;
    float m = sl;

    for (int e = e0; e < e1; ++e) {
        float2 w2 = eea[e];
        if (MASKED && !(w2.x > 1.0f)) continue;
        int s = esrc[e];
        float al = sterm[s * 16 + h] + dt + w2.x * q0 + w2.y * q1;
        al = al >= 0.f ? al : 0.2f * al;
        m = fmaxf(m, al);
    }

    float den = __expf(sl - m);
    float n0, n1, n2, n3, n4;
    {
        const float* xr = xp + (size_t)d * 80 + h * 5;
        n0 = den * xr[0]; n1 = den * xr[1]; n2 = den * xr[2]; n3 = den * xr[3]; n4 = den * xr[4];
    }
    for (int e = e0; e < e1; ++e) {
        float2 w2 = eea[e];
        if (MASKED && !(w2.x > 1.0f)) continue;
        int s = esrc[e];
        float al = sterm[s * 16 + h] + dt + w2.x * q0 + w2.y * q1;
        al = al >= 0.f ? al : 0.2f * al;
        float w = __expf(al - m);
        den += w;
        const float* xr = xp + (size_t)s * 80 + h * 5;
        n0 += w * xr[0]; n1 += w * xr[1]; n2 += w * xr[2]; n3 += w * xr[3]; n4 += w * xr[4];
    }
    float inv = 1.0f / den;
    float* orow = hout + (size_t)d * 80 + h * 5;
    const float* br = bias + h * 5;
    orow[0] = n0 * inv + br[0];
    orow[1] = n1 * inv + br[1];
    orow[2] = n2 * inv + br[2];
    orow[3] = n3 * inv + br[3];
    orow[4] = n4 * inv + br[4];
}

// ---- scatter-max pool by timing bin ----
__global__ void k_pool(const float* __restrict__ x, const float* __restrict__ h2,
                       unsigned* __restrict__ pool, int N) {
    int i = blockIdx.x * blockDim.x + threadIdx.x;   // n*80 + ch
    if (i >= N * 80) return;
    int n = i / 80, ch = i % 80;
    int t = (int)x[(size_t)n * 5 + 2];               // timing bin, 0..499
    atomic_max_u32(&pool[t * 80 + ch], fenc(h2[i]));
}

__global__ void k_pool_dec(unsigned* __restrict__ pool, int total) {
    int i = blockIdx.x * blockDim.x + threadIdx.x;
    if (i >= total) return;
    unsigned u = pool[i];
    float f = (u == 0u) ? 0.f : fdec(u);             // empty segment -> 0
    ((float*)pool)[i] = f;
}

// ---- strided conv1d, k=10, stride=2, pad=1, + leaky 0.01 ----
__global__ void k_conv(const float* __restrict__ in, const float* __restrict__ w,
                       const float* __restrict__ b, float* __restrict__ out,
                       int Bn, int IC, int Lin, int OC, int Lout) {
    int i = blockIdx.x * blockDim.x + threadIdx.x;
    if (i >= Bn * OC * Lout) return;
    int t = i % Lout, oc = (i / Lout) % OC, g = i / (OC * Lout);
    float s = b[oc];
    for (int ic = 0; ic < IC; ++ic) {
        const float* ir = in + (size_t)g * IC * Lin + (size_t)ic * Lin;
        const float* wr = w + (size_t)oc * IC * 10 + ic * 10;
        #pragma unroll
        for (int k = 0; k < 10; ++k) {
            int p = 2 * t + k - 1;
            if (p >= 0 && p < Lin) s += ir[p] * wr[k];
        }
    }
    out[i] = s >= 0.f ? s : 0.01f * s;
}

// ---- maxpool1d(k=10,s=10) over L=57 -> 5, flatten to [B,80] ----
__global__ void k_maxpool(const float* __restrict__ c3, float* __restrict__ zf, int Bn) {
    int i = blockIdx.x * blockDim.x + threadIdx.x;
    if (i >= Bn * 80) return;
    int g = i / 80, r = i % 80, ch = r / 5, wd = r % 5;
    const float* p = c3 + (size_t)g * 16 * 57 + ch * 57 + wd * 10;
    float m = p[0];
    #pragma unroll
    for (int k = 1; k < 10; ++k) m = fmaxf(m, p[k]);
    zf[i] = m;
}

// ---- 80->128->128->1 MLP, leaky 0.01, optional tanh; one block per graph ----
__global__ void k_mlp(const float* __restrict__ zf,
                      const float* __restrict__ w1, const float* __restrict__ b1,
                      const float* __restrict__ w2, const float* __restrict__ b2,
                      const float* __restrict__ w3, const float* __restrict__ b3,
                      float* __restrict__ out, int which) {
    __shared__ float zin[80], h1s[128], h2s[128];
    int g = blockIdx.x, j = threadIdx.x;
    if (j < 80) zin[j] = zf[g * 80 + j];
    __syncthreads();
    float s = b1[j];
    for (int k = 0; k < 80; ++k) s += zin[k] * w1[j * 80 + k];
    h1s[j] = s >= 0.f ? s : 0.01f * s;
    __syncthreads();
    s = b2[j];
    for (int k = 0; k < 128; ++k) s += h1s[k] * w2[j * 128 + k];
    h2s[j] = s >= 0.f ? s : 0.01f * s;
    __syncthreads();
    if (j == 0) {
        float o = b3[0];
        for (int k = 0; k < 128; ++k) o += h2s[k] * w3[k];
        if (which == 0) o = tanhf(o);
        out[g * 3 + which] = o;
    }
}

extern "C" void kernel_launch(void* const* d_in, const int* in_sizes, int n_in,
                              void* d_out, int out_size, void* d_ws, size_t ws_size,
                              hipStream_t stream) {
    const float* x     = (const float*)d_in[0];
    const float* ea    = (const float*)d_in[1];
    const float* g1_W  = (const float*)d_in[2];
    const float* g1_We = (const float*)d_in[3];
    const float* g1_as = (const float*)d_in[4];
    const float* g1_ad = (const float*)d_in[5];
    const float* g1_ae = (const float*)d_in[6];
    const float* g1_b  = (const float*)d_in[7];
    const float* g2_W  = (const float*)d_in[8];
    const float* g2_We = (const float*)d_in[9];
    const float* g2_as = (const float*)d_in[10];
    const float* g2_ad = (const float*)d_in[11];
    const float* g2_ae = (const float*)d_in[12];
    const float* g2_b  = (const float*)d_in[13];
    const float* c1w = (const float*)d_in[14]; const float* c1b = (const float*)d_in[15];
    const float* c2w = (const float*)d_in[16]; const float* c2b = (const float*)d_in[17];
    const float* c3w = (const float*)d_in[18]; const float* c3b = (const float*)d_in[19];
    const int*   eidx = (const int*)d_in[38];
    float* out = (float*)d_out;

    const int N = in_sizes[0] / 5;
    const int E = in_sizes[38] / 2;
    const int B = out_size / 3, SIZE = 500;
    const int* src = eidx;
    const int* dst = eidx + E;

    // ---- workspace layout (float units, each offset rounded to 4) ----
    float* ws = (float*)d_ws;
    size_t o = 0;
    auto alloc = [&](size_t n) { float* p = ws + o; o = (o + n + 3) & ~(size_t)3; return p; };
    float*    A     = alloc((size_t)N * 80);          // xp (projected features)
    float*    Hbuf  = alloc((size_t)N * 80);          // h1 then h2
    float*    sterm = alloc((size_t)N * 16);
    float*    dterm = alloc((size_t)N * 16);
    float*    q     = alloc(32);
    int*      off   = (int*)alloc((size_t)N + 1);
    int*      cur   = (int*)alloc((size_t)N);
    int*      bsum  = (int*)alloc(512);
    int*      esrc  = (int*)alloc((size_t)E);
    float2*   eea   = (float2*)alloc((size_t)E * 2);
    unsigned* pool  = (unsigned*)alloc((size_t)B * SIZE * 80);
    float*    c1    = alloc((size_t)B * 16 * 247);
    float*    c2    = alloc((size_t)B * 16 * 120);
    float*    c3    = alloc((size_t)B * 16 * 57);
    float*    zf    = alloc((size_t)B * 80);

    const int BS = 256;
    auto blocks = [&](long long n) { return (int)((n + BS - 1) / BS); };
    const int G = (N + SCAN_B - 1) / SCAN_B;          // <= 512 for N <= 131072

    // ================= CSR build (shared by both layers) =================
    hipMemsetAsync(cur, 0, (size_t)N * 4, stream);
    k_hist<<<blocks(E), BS, 0, stream>>>(dst, cur, E);
    k_bsum<<<G, SCAN_B, 0, stream>>>(cur, bsum, N);
    k_bscan<<<1, 512, 0, stream>>>(bsum, G);
    k_apply<<<G, SCAN_B, 0, stream>>>(cur, off, cur, bsum, N);
    k_scatter<<<blocks(E), BS, 0, stream>>>(src, dst, ea, cur, esrc, eea, E);

    // ================= GAT layer 1 =================
    k_proj<5><<<blocks((long long)N * 80), BS, 0, stream>>>(x, g1_W, A, N);
    k_terms<<<blocks((long long)N * 16), BS, 0, stream>>>(A, g1_as, g1_ad, sterm, dterm, N);
    k_q<<<1, 16, 0, stream>>>(g1_We, g1_ae, q);
    k_gat<false><<<blocks((long long)N * 16), BS, 0, stream>>>(
        off, esrc, eea, sterm, dterm, q, A, g1_b, Hbuf, N);

    // ================= GAT layer 2 =================
    k_proj<80><<<blocks((long long)N * 80), BS, 0, stream>>>(Hbuf, g2_W, A, N);
    k_terms<<<blocks((long long)N * 16), BS, 0, stream>>>(A, g2_as, g2_ad, sterm, dterm, N);
    k_q<<<1, 16, 0, stream>>>(g2_We, g2_ae, q);
    k_gat<true><<<blocks((long long)N * 16), BS, 0, stream>>>(
        off, esrc, eea, sterm, dterm, q, A, g2_b, Hbuf, N);

    // ================= pooling =================
    hipMemsetAsync(pool, 0, (size_t)B * SIZE * 80 * 4, stream);
    k_pool<<<blocks((long long)N * 80), BS, 0, stream>>>(x, Hbuf, pool, N);
    k_pool_dec<<<blocks((long long)B * SIZE * 80), BS, 0, stream>>>(pool, B * SIZE * 80);
    float* poolf = (float*)pool;   // flat [B*500*80]; conv1 reads the reshape view

    // ================= conv tower =================
    k_conv<<<blocks((long long)B * 16 * 247), BS, 0, stream>>>(poolf, c1w, c1b, c1, B, 80, 500, 16, 247);
    k_conv<<<blocks((long long)B * 16 * 120), BS, 0, stream>>>(c1,    c2w, c2b, c2, B, 16, 247, 16, 120);
    k_conv<<<blocks((long long)B * 16 * 57),  BS, 0, stream>>>(c2,    c3w, c3b, c3, B, 16, 120, 16, 57);
    k_maxpool<<<blocks((long long)B * 80), BS, 0, stream>>>(c3, zf, B);

    // ================= heads =================
    k_mlp<<<B, 128, 0, stream>>>(zf, (const float*)d_in[20], (const float*)d_in[21],
                                 (const float*)d_in[22], (const float*)d_in[23],
                                 (const float*)d_in[24], (const float*)d_in[25], out, 0);
    k_mlp<<<B, 128, 0, stream>>>(zf, (const float*)d_in[26], (const float*)d_in[27],
                                 (const float*)d_in[28], (const float*)d_in[29],
                                 (const float*)d_in[30], (const float*)d_in[31], out, 1);
    k_mlp<<<B, 128, 0, stream>>>(zf, (const float*)d_in[32], (const float*)d_in[33],
                                 (const float*)d_in[34], (const float*)d_in[35],
                                 (const float*)d_in[36], (const float*)d_in[37], out, 2);
}

// Round 3
// 807.025 us; speedup vs baseline: 4.7094x; 1.2717x over previous
//
#include <hip/hip_runtime.h>
#include <math.h>

#define DEV static __device__ __forceinline__

// ---- ordered-uint encoding for float atomic max ----
DEV unsigned fenc(float f) {
    unsigned u = __float_as_uint(f);
    return (u & 0x80000000u) ? ~u : (u | 0x80000000u);
}
DEV float fdec(unsigned u) {
    return __uint_as_float((u & 0x80000000u) ? (u ^ 0x80000000u) : ~u);
}
DEV void atomic_max_u32(unsigned* p, unsigned v) {
    __hip_atomic_fetch_max(p, v, __ATOMIC_RELAXED, __HIP_MEMORY_SCOPE_AGENT);
}

// ---- q[h] = sum_c We[h*5+c, 0/1] * a_e[h,c]  (edge-attr folding) ----
__global__ void k_q(const float* __restrict__ We, const float* __restrict__ a_e,
                    float* __restrict__ q) {
    int h = threadIdx.x;
    if (h >= 16) return;
    float q0 = 0.f, q1 = 0.f;
    #pragma unroll
    for (int c = 0; c < 5; ++c) {
        q0 += We[(h * 5 + c) * 2 + 0] * a_e[h * 5 + c];
        q1 += We[(h * 5 + c) * 2 + 1] * a_e[h * 5 + c];
    }
    q[h] = q0; q[16 + h] = q1;
}

// ================= layer-1 projection (K=5) fused with attn terms =================
// xp is PADDED: [N][16 heads][8] (5 used + 3 pad) so gathers are 32B-aligned.
__global__ void k_proj5t(const float* __restrict__ x, const float* __restrict__ W,
                         const float* __restrict__ a_s, const float* __restrict__ a_d,
                         float* __restrict__ xp, float* __restrict__ sterm,
                         float* __restrict__ dterm, int N) {
    int i = blockIdx.x * blockDim.x + threadIdx.x;   // n*16 + h
    if (i >= N * 16) return;
    int n = i >> 4, h = i & 15;
    float xr[5];
    #pragma unroll
    for (int j = 0; j < 5; ++j) xr[j] = x[(size_t)n * 5 + j];
    float o[5];
    #pragma unroll
    for (int c = 0; c < 5; ++c) {
        const float* wr = W + (size_t)(h * 5 + c) * 5;
        float s = 0.f;
        #pragma unroll
        for (int j = 0; j < 5; ++j) s += xr[j] * wr[j];
        o[c] = s;
    }
    float* orow = xp + ((size_t)n << 7) + (h << 3);
    *(float4*)orow = make_float4(o[0], o[1], o[2], o[3]);
    orow[4] = o[4];
    float ss = 0.f, sd = 0.f;
    #pragma unroll
    for (int c = 0; c < 5; ++c) { ss += o[c] * a_s[h * 5 + c]; sd += o[c] * a_d[h * 5 + c]; }
    sterm[i] = ss; dterm[i] = sd;
}

// ================= layer-2 projection (K=80) : LDS-tiled GEMM =================
// 128 nodes x 80 oc per block; thread (h=tid&15, ng=tid>>4) owns 8 nodes x 5 oc.
// Fuses sterm/dterm epilogue. Output xp padded [N][128].
__global__ __launch_bounds__(256) void k_proj80t(
    const float* __restrict__ in,    // [N][80]
    const float* __restrict__ W,     // [80][80]
    const float* __restrict__ a_s, const float* __restrict__ a_d,
    float* __restrict__ xp,          // [N][128] padded
    float* __restrict__ sterm, float* __restrict__ dterm, int N) {
    __shared__ float XS[16 * 136];   // [kk][node], stride 136 (2-way max on store)
    __shared__ float WS[16 * 81];    // [kk][oc],   stride 81 (conflict-free)
    int tid = threadIdx.x;
    int n0 = blockIdx.x * 128;
    int h = tid & 15, ng = tid >> 4;

    float acc[8][5];
    #pragma unroll
    for (int j = 0; j < 8; ++j)
        #pragma unroll
        for (int c = 0; c < 5; ++c) acc[j][c] = 0.f;

    for (int k0 = 0; k0 < 80; k0 += 16) {
        __syncthreads();
        {   // stage XS: rows n0..n0+127, cols k0..k0+15, transposed into LDS
            int r = tid >> 1;
            int halfk = (tid & 1) * 8;
            int n = n0 + r; if (n >= N) n = N - 1;
            const float* p = in + (size_t)n * 80 + k0 + halfk;
            float4 v0 = *(const float4*)p;
            float4 v1 = *(const float4*)(p + 4);
            float vv[8] = {v0.x, v0.y, v0.z, v0.w, v1.x, v1.y, v1.z, v1.w};
            #pragma unroll
            for (int j = 0; j < 8; ++j) XS[(halfk + j) * 136 + r] = vv[j];
        }
        {   // stage WS: W[oc][k0..k0+15] transposed
            #pragma unroll
            for (int i = 0; i < 5; ++i) {
                int j = tid + i * 256;        // 0..1279
                int oc = j >> 4, kk = j & 15;
                WS[kk * 81 + oc] = W[(size_t)oc * 80 + k0 + kk];
            }
        }
        __syncthreads();
        #pragma unroll
        for (int kk = 0; kk < 16; ++kk) {
            float4 xa = *(const float4*)&XS[kk * 136 + ng * 8];
            float4 xb = *(const float4*)&XS[kk * 136 + ng * 8 + 4];
            float wv[5];
            #pragma unroll
            for (int c = 0; c < 5; ++c) wv[c] = WS[kk * 81 + h * 5 + c];
            float xv[8] = {xa.x, xa.y, xa.z, xa.w, xb.x, xb.y, xb.z, xb.w};
            #pragma unroll
            for (int j = 0; j < 8; ++j)
                #pragma unroll
                for (int c = 0; c < 5; ++c) acc[j][c] += xv[j] * wv[c];
        }
    }
    float as_[5], ad_[5];
    #pragma unroll
    for (int c = 0; c < 5; ++c) { as_[c] = a_s[h * 5 + c]; ad_[c] = a_d[h * 5 + c]; }
    #pragma unroll
    for (int j = 0; j < 8; ++j) {
        int n = n0 + ng * 8 + j;
        if (n < N) {
            float* orow = xp + ((size_t)n << 7) + (h << 3);
            *(float4*)orow = make_float4(acc[j][0], acc[j][1], acc[j][2], acc[j][3]);
            orow[4] = acc[j][4];
            float ss = 0.f, sd = 0.f;
            #pragma unroll
            for (int c = 0; c < 5; ++c) { ss += acc[j][c] * as_[c]; sd += acc[j][c] * ad_[c]; }
            sterm[n * 16 + h] = ss; dterm[n * 16 + h] = sd;
        }
    }
}

// ================= CSR build (by dst) =================
__global__ void k_hist(const int* __restrict__ dst, int* __restrict__ deg, int E) {
    int e = blockIdx.x * blockDim.x + threadIdx.x;
    if (e >= E) return;
    __hip_atomic_fetch_add(&deg[dst[e]], 1, __ATOMIC_RELAXED, __HIP_MEMORY_SCOPE_AGENT);
}

#define SCAN_B 256
__global__ void k_bsum(const int* __restrict__ deg, int* __restrict__ bsum, int N) {
    __shared__ int sm[SCAN_B];
    int i = blockIdx.x * SCAN_B + threadIdx.x;
    sm[threadIdx.x] = (i < N) ? deg[i] : 0;
    __syncthreads();
    for (int s = SCAN_B / 2; s > 0; s >>= 1) {
        if (threadIdx.x < s) sm[threadIdx.x] += sm[threadIdx.x + s];
        __syncthreads();
    }
    if (threadIdx.x == 0) bsum[blockIdx.x] = sm[0];
}

__global__ void k_bscan(int* __restrict__ bsum, int G) {
    __shared__ int sm[512];
    int t = threadIdx.x;
    int orig = (t < G) ? bsum[t] : 0;
    sm[t] = orig;
    __syncthreads();
    for (int s = 1; s < 512; s <<= 1) {
        int v = (t >= s) ? sm[t - s] : 0;
        __syncthreads();
        sm[t] += v;
        __syncthreads();
    }
    if (t < G) bsum[t] = sm[t] - orig;
}

__global__ void k_apply(const int* __restrict__ deg, int* __restrict__ off,
                        int* __restrict__ cur, const int* __restrict__ bsum, int N) {
    __shared__ int sm[SCAN_B];
    int i = blockIdx.x * SCAN_B + threadIdx.x;
    int v = (i < N) ? deg[i] : 0;
    sm[threadIdx.x] = v;
    __syncthreads();
    for (int s = 1; s < SCAN_B; s <<= 1) {
        int t = (threadIdx.x >= s) ? sm[threadIdx.x - s] : 0;
        __syncthreads();
        sm[threadIdx.x] += t;
        __syncthreads();
    }
    if (i < N) {
        int excl = bsum[blockIdx.x] + sm[threadIdx.x] - v;
        off[i] = excl;
        cur[i] = excl;
        if (i == N - 1) off[N] = excl + v;
    }
}

__global__ void k_scatter(const int* __restrict__ src, const int* __restrict__ dst,
                          const float* __restrict__ ea, int* __restrict__ cur,
                          int* __restrict__ esrc, float2* __restrict__ eea, int E) {
    int e = blockIdx.x * blockDim.x + threadIdx.x;
    if (e >= E) return;
    int d = dst[e];
    int p = __hip_atomic_fetch_add(&cur[d], 1, __ATOMIC_RELAXED, __HIP_MEMORY_SCOPE_AGENT);
    esrc[p] = src[e];
    eea[p] = make_float2(ea[2 * e], ea[2 * e + 1]);
}

// ================= fused GAT aggregation: single-pass online softmax =================
// one thread per (dst node, head); xp is padded [N][128].
template<bool MASKED>
__global__ void k_gat(const int* __restrict__ off, const int* __restrict__ esrc,
                      const float2* __restrict__ eea,
                      const float* __restrict__ sterm, const float* __restrict__ dterm,
                      const float* __restrict__ q, const float* __restrict__ xp,
                      const float* __restrict__ bias, float* __restrict__ hout, int N) {
    int i = blockIdx.x * blockDim.x + threadIdx.x;   // d*16 + h
    if (i >= N * 16) return;
    int d = i >> 4, h = i & 15;
    float q0 = q[h], q1 = q[16 + h];
    float dt = dterm[i];
    int e0 = off[d], e1 = off[d + 1];

    // self-loop (ea = 0) seeds the online-softmax state
    float sl = sterm[i] + dt;
    sl = sl >= 0.f ? sl : 0.2f * sl;
    float m = sl, den = 1.f;
    float n0, n1, n2, n3, n4;
    {
        const float* xd = xp + ((size_t)d << 7) + (h << 3);
        float4 v = *(const float4*)xd;
        n0 = v.x; n1 = v.y; n2 = v.z; n3 = v.w; n4 = xd[4];
    }

    int s_nxt = 0; float2 w_nxt = make_float2(0.f, 0.f);
    if (e0 < e1) { s_nxt = esrc[e0]; w_nxt = eea[e0]; }
    for (int e = e0; e < e1; ++e) {
        int s = s_nxt; float2 w2 = w_nxt;
        if (e + 1 < e1) { s_nxt = esrc[e + 1]; w_nxt = eea[e + 1]; }
        if (MASKED && !(w2.x > 1.0f)) continue;
        float al = sterm[s * 16 + h] + dt + w2.x * q0 + w2.y * q1;
        al = al >= 0.f ? al : 0.2f * al;
        const float* xr = xp + ((size_t)s << 7) + (h << 3);
        float4 xv = *(const float4*)xr;
        float x4 = xr[4];
        float nm = fmaxf(m, al);
        float c = __expf(m - nm);
        float w = __expf(al - nm);
        den = den * c + w;
        n0 = n0 * c + w * xv.x;
        n1 = n1 * c + w * xv.y;
        n2 = n2 * c + w * xv.z;
        n3 = n3 * c + w * xv.w;
        n4 = n4 * c + w * x4;
        m = nm;
    }
    float inv = 1.0f / den;
    float* orow = hout + (size_t)d * 80 + h * 5;
    const float* br = bias + h * 5;
    orow[0] = n0 * inv + br[0];
    orow[1] = n1 * inv + br[1];
    orow[2] = n2 * inv + br[2];
    orow[3] = n3 * inv + br[3];
    orow[4] = n4 * inv + br[4];
}

// ---- scatter-max pool by timing bin ----
__global__ void k_pool(const float* __restrict__ x, const float* __restrict__ h2,
                       unsigned* __restrict__ pool, int N) {
    int i = blockIdx.x * blockDim.x + threadIdx.x;   // n*80 + ch
    if (i >= N * 80) return;
    int n = i / 80, ch = i % 80;
    int t = (int)x[(size_t)n * 5 + 2];               // timing bin, 0..499
    atomic_max_u32(&pool[t * 80 + ch], fenc(h2[i]));
}

__global__ void k_pool_dec(unsigned* __restrict__ pool, int total) {
    int i = blockIdx.x * blockDim.x + threadIdx.x;
    if (i >= total) return;
    unsigned u = pool[i];
    float f = (u == 0u) ? 0.f : fdec(u);             // empty segment -> 0
    ((float*)pool)[i] = f;
}

// ---- strided conv1d, k=10, stride=2, pad=1, + leaky 0.01 ----
__global__ void k_conv(const float* __restrict__ in, const float* __restrict__ w,
                       const float* __restrict__ b, float* __restrict__ out,
                       int Bn, int IC, int Lin, int OC, int Lout) {
    int i = blockIdx.x * blockDim.x + threadIdx.x;
    if (i >= Bn * OC * Lout) return;
    int t = i % Lout, oc = (i / Lout) % OC, g = i / (OC * Lout);
    float s = b[oc];
    for (int ic = 0; ic < IC; ++ic) {
        const float* ir = in + (size_t)g * IC * Lin + (size_t)ic * Lin;
        const float* wr = w + (size_t)oc * IC * 10 + ic * 10;
        #pragma unroll
        for (int k = 0; k < 10; ++k) {
            int p = 2 * t + k - 1;
            if (p >= 0 && p < Lin) s += ir[p] * wr[k];
        }
    }
    out[i] = s >= 0.f ? s : 0.01f * s;
}

// ---- maxpool1d(k=10,s=10) over L=57 -> 5, flatten to [B,80] ----
__global__ void k_maxpool(const float* __restrict__ c3, float* __restrict__ zf, int Bn) {
    int i = blockIdx.x * blockDim.x + threadIdx.x;
    if (i >= Bn * 80) return;
    int g = i / 80, r = i % 80, ch = r / 5, wd = r % 5;
    const float* p = c3 + (size_t)g * 16 * 57 + ch * 57 + wd * 10;
    float m = p[0];
    #pragma unroll
    for (int k = 1; k < 10; ++k) m = fmaxf(m, p[k]);
    zf[i] = m;
}

// ---- 80->128->128->1 MLP, leaky 0.01, optional tanh; one block per graph ----
__global__ void k_mlp(const float* __restrict__ zf,
                      const float* __restrict__ w1, const float* __restrict__ b1,
                      const float* __restrict__ w2, const float* __restrict__ b2,
                      const float* __restrict__ w3, const float* __restrict__ b3,
                      float* __restrict__ out, int which) {
    __shared__ float zin[80], h1s[128], h2s[128];
    int g = blockIdx.x, j = threadIdx.x;
    if (j < 80) zin[j] = zf[g * 80 + j];
    __syncthreads();
    float s = b1[j];
    for (int k = 0; k < 80; ++k) s += zin[k] * w1[j * 80 + k];
    h1s[j] = s >= 0.f ? s : 0.01f * s;
    __syncthreads();
    s = b2[j];
    for (int k = 0; k < 128; ++k) s += h1s[k] * w2[j * 128 + k];
    h2s[j] = s >= 0.f ? s : 0.01f * s;
    __syncthreads();
    if (j == 0) {
        float o = b3[0];
        for (int k = 0; k < 128; ++k) o += h2s[k] * w3[k];
        if (which == 0) o = tanhf(o);
        out[g * 3 + which] = o;
    }
}

extern "C" void kernel_launch(void* const* d_in, const int* in_sizes, int n_in,
                              void* d_out, int out_size, void* d_ws, size_t ws_size,
                              hipStream_t stream) {
    const float* x     = (const float*)d_in[0];
    const float* ea    = (const float*)d_in[1];
    const float* g1_W  = (const float*)d_in[2];
    const float* g1_We = (const float*)d_in[3];
    const float* g1_as = (const float*)d_in[4];
    const float* g1_ad = (const float*)d_in[5];
    const float* g1_ae = (const float*)d_in[6];
    const float* g1_b  = (const float*)d_in[7];
    const float* g2_W  = (const float*)d_in[8];
    const float* g2_We = (const float*)d_in[9];
    const float* g2_as = (const float*)d_in[10];
    const float* g2_ad = (const float*)d_in[11];
    const float* g2_ae = (const float*)d_in[12];
    const float* g2_b  = (const float*)d_in[13];
    const float* c1w = (const float*)d_in[14]; const float* c1b = (const float*)d_in[15];
    const float* c2w = (const float*)d_in[16]; const float* c2b = (const float*)d_in[17];
    const float* c3w = (const float*)d_in[18]; const float* c3b = (const float*)d_in[19];
    const int*   eidx = (const int*)d_in[38];
    float* out = (float*)d_out;

    const int N = in_sizes[0] / 5;
    const int E = in_sizes[38] / 2;
    const int B = out_size / 3, SIZE = 500;
    const int* src = eidx;
    const int* dst = eidx + E;

    // ---- workspace layout (float units, each offset rounded to 4) ----
    float* ws = (float*)d_ws;
    size_t o = 0;
    auto alloc = [&](size_t n) { float* p = ws + o; o = (o + n + 3) & ~(size_t)3; return p; };
    float*    A     = alloc((size_t)N * 128);         // xp, PADDED [N][16][8]
    float*    Hbuf  = alloc((size_t)N * 80);          // h1 then h2 (dense)
    float*    sterm = alloc((size_t)N * 16);
    float*    dterm = alloc((size_t)N * 16);
    float*    q     = alloc(32);
    int*      off   = (int*)alloc((size_t)N + 1);
    int*      cur   = (int*)alloc((size_t)N);
    int*      bsum  = (int*)alloc(512);
    int*      esrc  = (int*)alloc((size_t)E);
    float2*   eea   = (float2*)alloc((size_t)E * 2);
    unsigned* pool  = (unsigned*)alloc((size_t)B * SIZE * 80);
    float*    c1    = alloc((size_t)B * 16 * 247);
    float*    c2    = alloc((size_t)B * 16 * 120);
    float*    c3    = alloc((size_t)B * 16 * 57);
    float*    zf    = alloc((size_t)B * 80);

    const int BS = 256;
    auto blocks = [&](long long n) { return (int)((n + BS - 1) / BS); };
    const int G = (N + SCAN_B - 1) / SCAN_B;          // <= 512 for N <= 131072

    // ================= CSR build (shared by both layers) =================
    hipMemsetAsync(cur, 0, (size_t)N * 4, stream);
    k_hist<<<blocks(E), BS, 0, stream>>>(dst, cur, E);
    k_bsum<<<G, SCAN_B, 0, stream>>>(cur, bsum, N);
    k_bscan<<<1, 512, 0, stream>>>(bsum, G);
    k_apply<<<G, SCAN_B, 0, stream>>>(cur, off, cur, bsum, N);
    k_scatter<<<blocks(E), BS, 0, stream>>>(src, dst, ea, cur, esrc, eea, E);

    // ================= GAT layer 1 =================
    k_proj5t<<<blocks((long long)N * 16), BS, 0, stream>>>(x, g1_W, g1_as, g1_ad,
                                                           A, sterm, dterm, N);
    k_q<<<1, 16, 0, stream>>>(g1_We, g1_ae, q);
    k_gat<false><<<blocks((long long)N * 16), BS, 0, stream>>>(
        off, esrc, eea, sterm, dterm, q, A, g1_b, Hbuf, N);

    // ================= GAT layer 2 =================
    k_proj80t<<<(N + 127) / 128, 256, 0, stream>>>(Hbuf, g2_W, g2_as, g2_ad,
                                                   A, sterm, dterm, N);
    k_q<<<1, 16, 0, stream>>>(g2_We, g2_ae, q);
    k_gat<true><<<blocks((long long)N * 16), BS, 0, stream>>>(
        off, esrc, eea, sterm, dterm, q, A, g2_b, Hbuf, N);

    // ================= pooling =================
    hipMemsetAsync(pool, 0, (size_t)B * SIZE * 80 * 4, stream);
    k_pool<<<blocks((long long)N * 80), BS, 0, stream>>>(x, Hbuf, pool, N);
    k_pool_dec<<<blocks((long long)B * SIZE * 80), BS, 0, stream>>>(pool, B * SIZE * 80);
    float* poolf = (float*)pool;   // flat [B*500*80]; conv1 reads the reshape view

    // ================= conv tower =================
    k_conv<<<blocks((long long)B * 16 * 247), BS, 0, stream>>>(poolf, c1w, c1b, c1, B, 80, 500, 16, 247);
    k_conv<<<blocks((long long)B * 16 * 120), BS, 0, stream>>>(c1,    c2w, c2b, c2, B, 16, 247, 16, 120);
    k_conv<<<blocks((long long)B * 16 * 57),  BS, 0, stream>>>(c2,    c3w, c3b, c3, B, 16, 120, 16, 57);
    k_maxpool<<<blocks((long long)B * 80), BS, 0, stream>>>(c3, zf, B);

    // ================= heads =================
    k_mlp<<<B, 128, 0, stream>>>(zf, (const float*)d_in[20], (const float*)d_in[21],
                                 (const float*)d_in[22], (const float*)d_in[23],
                                 (const float*)d_in[24], (const float*)d_in[25], out, 0);
    k_mlp<<<B, 128, 0, stream>>>(zf, (const float*)d_in[26], (const float*)d_in[27],
                                 (const float*)d_in[28], (const float*)d_in[29],
                                 (const float*)d_in[30], (const float*)d_in[31], out, 1);
    k_mlp<<<B, 128, 0, stream>>>(zf, (const float*)d_in[32], (const float*)d_in[33],
                                 (const float*)d_in[34], (const float*)d_in[35],
                                 (const float*)d_in[36], (const float*)d_in[37], out, 2);
}

// Round 4
// 620.163 us; speedup vs baseline: 6.1283x; 1.3013x over previous
//
#include <hip/hip_runtime.h>
#include <math.h>

#define DEV static __device__ __forceinline__

// ---- ordered-uint encoding for float atomic max ----
DEV unsigned fenc(float f) {
    unsigned u = __float_as_uint(f);
    return (u & 0x80000000u) ? ~u : (u | 0x80000000u);
}
DEV float fdec(unsigned u) {
    return __uint_as_float((u & 0x80000000u) ? (u ^ 0x80000000u) : ~u);
}
DEV void atomic_max_u32(unsigned* p, unsigned v) {
    __hip_atomic_fetch_max(p, v, __ATOMIC_RELAXED, __HIP_MEMORY_SCOPE_AGENT);
}

// ================= layer-1 projection (K=5) fused with attn terms =================
// xp dense [N][80].
__global__ void k_proj5t(const float* __restrict__ x, const float* __restrict__ W,
                         const float* __restrict__ a_s, const float* __restrict__ a_d,
                         float* __restrict__ xp, float* __restrict__ sterm,
                         float* __restrict__ dterm, int N) {
    int i = blockIdx.x * blockDim.x + threadIdx.x;   // n*16 + h
    if (i >= N * 16) return;
    int n = i >> 4, h = i & 15;
    float xr[5];
    #pragma unroll
    for (int j = 0; j < 5; ++j) xr[j] = x[(size_t)n * 5 + j];
    float o[5];
    #pragma unroll
    for (int c = 0; c < 5; ++c) {
        const float* wr = W + (size_t)(h * 5 + c) * 5;
        float s = 0.f;
        #pragma unroll
        for (int j = 0; j < 5; ++j) s += xr[j] * wr[j];
        o[c] = s;
    }
    float* orow = xp + (size_t)n * 80 + h * 5;
    #pragma unroll
    for (int c = 0; c < 5; ++c) orow[c] = o[c];
    float ss = 0.f, sd = 0.f;
    #pragma unroll
    for (int c = 0; c < 5; ++c) { ss += o[c] * a_s[h * 5 + c]; sd += o[c] * a_d[h * 5 + c]; }
    sterm[i] = ss; dterm[i] = sd;
}

// ================= layer-2 projection (K=80) : LDS-tiled GEMM =================
// 128 nodes x 80 oc per block; thread (h=tid&15, ng=tid>>4) owns 8 nodes x 5 oc.
// Fuses sterm/dterm epilogue. Output xp dense [N][80].
__global__ __launch_bounds__(256) void k_proj80t(
    const float* __restrict__ in,    // [N][80]
    const float* __restrict__ W,     // [80][80]
    const float* __restrict__ a_s, const float* __restrict__ a_d,
    float* __restrict__ xp,          // [N][80] dense
    float* __restrict__ sterm, float* __restrict__ dterm, int N) {
    __shared__ float XS[16 * 136];   // [kk][node]
    __shared__ float WS[16 * 81];    // [kk][oc]
    int tid = threadIdx.x;
    int n0 = blockIdx.x * 128;
    int h = tid & 15, ng = tid >> 4;

    float acc[8][5];
    #pragma unroll
    for (int j = 0; j < 8; ++j)
        #pragma unroll
        for (int c = 0; c < 5; ++c) acc[j][c] = 0.f;

    for (int k0 = 0; k0 < 80; k0 += 16) {
        __syncthreads();
        {   // stage XS: rows n0..n0+127, cols k0..k0+15, transposed into LDS
            int r = tid >> 1;
            int halfk = (tid & 1) * 8;
            int n = n0 + r; if (n >= N) n = N - 1;
            const float* p = in + (size_t)n * 80 + k0 + halfk;
            float4 v0 = *(const float4*)p;
            float4 v1 = *(const float4*)(p + 4);
            float vv[8] = {v0.x, v0.y, v0.z, v0.w, v1.x, v1.y, v1.z, v1.w};
            #pragma unroll
            for (int j = 0; j < 8; ++j) XS[(halfk + j) * 136 + r] = vv[j];
        }
        {   // stage WS: W[oc][k0..k0+15] transposed
            #pragma unroll
            for (int i = 0; i < 5; ++i) {
                int j = tid + i * 256;        // 0..1279
                int oc = j >> 4, kk = j & 15;
                WS[kk * 81 + oc] = W[(size_t)oc * 80 + k0 + kk];
            }
        }
        __syncthreads();
        #pragma unroll
        for (int kk = 0; kk < 16; ++kk) {
            float4 xa = *(const float4*)&XS[kk * 136 + ng * 8];
            float4 xb = *(const float4*)&XS[kk * 136 + ng * 8 + 4];
            float wv[5];
            #pragma unroll
            for (int c = 0; c < 5; ++c) wv[c] = WS[kk * 81 + h * 5 + c];
            float xv[8] = {xa.x, xa.y, xa.z, xa.w, xb.x, xb.y, xb.z, xb.w};
            #pragma unroll
            for (int j = 0; j < 8; ++j)
                #pragma unroll
                for (int c = 0; c < 5; ++c) acc[j][c] += xv[j] * wv[c];
        }
    }
    float as_[5], ad_[5];
    #pragma unroll
    for (int c = 0; c < 5; ++c) { as_[c] = a_s[h * 5 + c]; ad_[c] = a_d[h * 5 + c]; }
    #pragma unroll
    for (int j = 0; j < 8; ++j) {
        int n = n0 + ng * 8 + j;
        if (n < N) {
            float* orow = xp + (size_t)n * 80 + h * 5;
            #pragma unroll
            for (int c = 0; c < 5; ++c) orow[c] = acc[j][c];
            float ss = 0.f, sd = 0.f;
            #pragma unroll
            for (int c = 0; c < 5; ++c) { ss += acc[j][c] * as_[c]; sd += acc[j][c] * ad_[c]; }
            sterm[n * 16 + h] = ss; dterm[n * 16 + h] = sd;
        }
    }
}

// ================= CSR build (by dst) =================
__global__ void k_hist(const int* __restrict__ dst, int* __restrict__ deg, int E) {
    int e = blockIdx.x * blockDim.x + threadIdx.x;
    if (e >= E) return;
    __hip_atomic_fetch_add(&deg[dst[e]], 1, __ATOMIC_RELAXED, __HIP_MEMORY_SCOPE_AGENT);
}

#define SCAN_B 256
__global__ void k_bsum(const int* __restrict__ deg, int* __restrict__ bsum, int N) {
    __shared__ int sm[SCAN_B];
    int i = blockIdx.x * SCAN_B + threadIdx.x;
    sm[threadIdx.x] = (i < N) ? deg[i] : 0;
    __syncthreads();
    for (int s = SCAN_B / 2; s > 0; s >>= 1) {
        if (threadIdx.x < s) sm[threadIdx.x] += sm[threadIdx.x + s];
        __syncthreads();
    }
    if (threadIdx.x == 0) bsum[blockIdx.x] = sm[0];
}

__global__ void k_bscan(int* __restrict__ bsum, int G) {
    __shared__ int sm[512];
    int t = threadIdx.x;
    int orig = (t < G) ? bsum[t] : 0;
    sm[t] = orig;
    __syncthreads();
    for (int s = 1; s < 512; s <<= 1) {
        int v = (t >= s) ? sm[t - s] : 0;
        __syncthreads();
        sm[t] += v;
        __syncthreads();
    }
    if (t < G) bsum[t] = sm[t] - orig;
}

__global__ void k_apply(const int* __restrict__ deg, int* __restrict__ off,
                        int* __restrict__ cur, const int* __restrict__ bsum, int N) {
    __shared__ int sm[SCAN_B];
    int i = blockIdx.x * SCAN_B + threadIdx.x;
    int v = (i < N) ? deg[i] : 0;
    sm[threadIdx.x] = v;
    __syncthreads();
    for (int s = 1; s < SCAN_B; s <<= 1) {
        int t = (threadIdx.x >= s) ? sm[threadIdx.x - s] : 0;
        __syncthreads();
        sm[threadIdx.x] += t;
        __syncthreads();
    }
    if (i < N) {
        int excl = bsum[blockIdx.x] + sm[threadIdx.x] - v;
        off[i] = excl;
        cur[i] = excl;
        if (i == N - 1) off[N] = excl + v;
    }
}

__global__ void k_scatter(const int* __restrict__ src, const int* __restrict__ dst,
                          const float* __restrict__ ea, int* __restrict__ cur,
                          int* __restrict__ esrc, float2* __restrict__ eea, int E) {
    int e = blockIdx.x * blockDim.x + threadIdx.x;
    if (e >= E) return;
    int d = dst[e];
    int p = __hip_atomic_fetch_add(&cur[d], 1, __ATOMIC_RELAXED, __HIP_MEMORY_SCOPE_AGENT);
    esrc[p] = src[e];
    eea[p] = make_float2(ea[2 * e], ea[2 * e + 1]);
}

// ================= fused GAT aggregation: single-pass online softmax =================
// one thread per (dst node, head); xp dense [N][80]; q folded in from We/a_e.
template<bool MASKED>
__global__ void k_gat(const int* __restrict__ off, const int* __restrict__ esrc,
                      const float2* __restrict__ eea,
                      const float* __restrict__ sterm, const float* __restrict__ dterm,
                      const float* __restrict__ We, const float* __restrict__ a_e,
                      const float* __restrict__ xp,
                      const float* __restrict__ bias, float* __restrict__ hout, int N) {
    int i = blockIdx.x * blockDim.x + threadIdx.x;   // d*16 + h
    if (i >= N * 16) return;
    int d = i >> 4, h = i & 15;
    float q0 = 0.f, q1 = 0.f;
    #pragma unroll
    for (int c = 0; c < 5; ++c) {
        float ae = a_e[h * 5 + c];
        q0 += We[(h * 5 + c) * 2 + 0] * ae;
        q1 += We[(h * 5 + c) * 2 + 1] * ae;
    }
    float dt = dterm[i];
    int e0 = off[d], e1 = off[d + 1];

    // self-loop (ea = 0) seeds the online-softmax state
    float sl = sterm[i] + dt;
    sl = sl >= 0.f ? sl : 0.2f * sl;
    float m = sl, den = 1.f;
    float n0, n1, n2, n3, n4;
    {
        const float* xd = xp + (size_t)d * 80 + h * 5;
        n0 = xd[0]; n1 = xd[1]; n2 = xd[2]; n3 = xd[3]; n4 = xd[4];
    }

    int s_nxt = 0; float2 w_nxt = make_float2(0.f, 0.f);
    if (e0 < e1) { s_nxt = esrc[e0]; w_nxt = eea[e0]; }
    for (int e = e0; e < e1; ++e) {
        int s = s_nxt; float2 w2 = w_nxt;
        if (e + 1 < e1) { s_nxt = esrc[e + 1]; w_nxt = eea[e + 1]; }
        if (MASKED && !(w2.x > 1.0f)) continue;
        float al = sterm[s * 16 + h] + dt + w2.x * q0 + w2.y * q1;
        al = al >= 0.f ? al : 0.2f * al;
        const float* xr = xp + (size_t)s * 80 + h * 5;
        float x0 = xr[0], x1 = xr[1], x2 = xr[2], x3 = xr[3], x4 = xr[4];
        float nm = fmaxf(m, al);
        float c = __expf(m - nm);
        float w = __expf(al - nm);
        den = den * c + w;
        n0 = n0 * c + w * x0;
        n1 = n1 * c + w * x1;
        n2 = n2 * c + w * x2;
        n3 = n3 * c + w * x3;
        n4 = n4 * c + w * x4;
        m = nm;
    }
    float inv = 1.0f / den;
    float* orow = hout + (size_t)d * 80 + h * 5;
    const float* br = bias + h * 5;
    orow[0] = n0 * inv + br[0];
    orow[1] = n1 * inv + br[1];
    orow[2] = n2 * inv + br[2];
    orow[3] = n3 * inv + br[3];
    orow[4] = n4 * inv + br[4];
}

// ---- scatter-max pool by timing bin ----
__global__ void k_pool(const float* __restrict__ x, const float* __restrict__ h2,
                       unsigned* __restrict__ pool, int N) {
    int i = blockIdx.x * blockDim.x + threadIdx.x;   // n*80 + ch
    if (i >= N * 80) return;
    int n = i / 80, ch = i % 80;
    int t = (int)x[(size_t)n * 5 + 2];               // timing bin, 0..499
    atomic_max_u32(&pool[t * 80 + ch], fenc(h2[i]));
}

// ================= conv1: LDS-staged, decode fused =================
// grid = B*4: (graph g, t-chunk of 62). in = encoded pool (u32), out c1 [B][16][247].
__global__ __launch_bounds__(256) void k_conv1(const unsigned* __restrict__ pool,
        const float* __restrict__ w, const float* __restrict__ b,
        float* __restrict__ c1) {
    __shared__ float XS[80 * 140];       // input window, row stride 140 (16B-aligned rows)
    __shared__ float WS[16 * 972];       // weights, oc stride 972 (aligned + bank-spread)
    int g = blockIdx.x >> 2, chunk = blockIdx.x & 3;
    int t0 = chunk * 62;
    int tid = threadIdx.x;
    for (int idx = tid; idx < 80 * 140; idx += 256) {
        int ic = idx / 140, j = idx % 140;
        int p = 2 * t0 - 1 + j;
        float v = 0.f;
        if (p >= 0 && p < 500) {
            unsigned u = pool[g * 40000 + ic * 500 + p];
            v = (u == 0u) ? 0.f : fdec(u);
        }
        XS[idx] = v;
    }
    for (int idx = tid; idx < 12800; idx += 256) {
        int oc = idx / 800, r = idx % 800;
        int ic = r / 10, k = r % 10;
        WS[oc * 972 + ic * 12 + k] = w[idx];
    }
    __syncthreads();
    int oc = tid >> 4, tg = tid & 15;    // thread covers t = t0 + 4*tg + j, j=0..3
    float acc0 = 0.f, acc1 = 0.f, acc2 = 0.f, acc3 = 0.f;
    for (int ic = 0; ic < 80; ++ic) {
        const float* xr = &XS[ic * 140 + 8 * tg];
        float4 xa = *(const float4*)xr;
        float4 xb = *(const float4*)(xr + 4);
        float4 xc = *(const float4*)(xr + 8);
        float4 xd = *(const float4*)(xr + 12);
        const float* wr = &WS[oc * 972 + ic * 12];
        float4 wa = *(const float4*)wr;
        float4 wb = *(const float4*)(wr + 4);
        float2 wc = *(const float2*)(wr + 8);
        float xv[16] = {xa.x, xa.y, xa.z, xa.w, xb.x, xb.y, xb.z, xb.w,
                        xc.x, xc.y, xc.z, xc.w, xd.x, xd.y, xd.z, xd.w};
        float wv[10] = {wa.x, wa.y, wa.z, wa.w, wb.x, wb.y, wb.z, wb.w, wc.x, wc.y};
        #pragma unroll
        for (int k = 0; k < 10; ++k) {
            acc0 += xv[k]     * wv[k];
            acc1 += xv[2 + k] * wv[k];
            acc2 += xv[4 + k] * wv[k];
            acc3 += xv[6 + k] * wv[k];
        }
    }
    float bb = b[oc];
    float accs[4] = {acc0, acc1, acc2, acc3};
    #pragma unroll
    for (int j = 0; j < 4; ++j) {
        int tt = 4 * tg + j;
        int t = t0 + tt;
        if (tt < 62 && t < 247) {
            float s = accs[j] + bb;
            c1[(size_t)g * 3952 + oc * 247 + t] = s >= 0.f ? s : 0.01f * s;
        }
    }
}

// ================= tail: conv2+conv3+maxpool+3 MLP heads, one block per graph =========
struct HeadW { const float *w1, *b1, *w2, *b2, *w3, *b3; };

__global__ __launch_bounds__(256) void k_tail(
        const float* __restrict__ c1,
        const float* __restrict__ w2c, const float* __restrict__ b2c,
        const float* __restrict__ w3c, const float* __restrict__ b3c,
        HeadW hw0, HeadW hw1, HeadW hw2, float* __restrict__ out) {
    __shared__ float Z1[16 * 248];
    __shared__ float Z2[16 * 121];
    __shared__ float Z3[16 * 58];
    __shared__ float ZF[80];
    __shared__ float HB[128];
    __shared__ float HC[128];
    int g = blockIdx.x, tid = threadIdx.x;
    for (int idx = tid; idx < 16 * 247; idx += 256) {
        int ic = idx / 247, t = idx % 247;
        Z1[ic * 248 + t] = c1[(size_t)g * 3952 + idx];
    }
    __syncthreads();
    for (int idx = tid; idx < 16 * 120; idx += 256) {       // conv2
        int oc = idx / 120, t = idx % 120;
        float s = b2c[oc];
        for (int ic = 0; ic < 16; ++ic) {
            const float* xr = &Z1[ic * 248];
            const float* wr = &w2c[(oc * 16 + ic) * 10];
            #pragma unroll
            for (int k = 0; k < 10; ++k) {
                int p = 2 * t + k - 1;
                if (p >= 0 && p < 247) s += xr[p] * wr[k];
            }
        }
        Z2[oc * 121 + t] = s >= 0.f ? s : 0.01f * s;
    }
    __syncthreads();
    for (int idx = tid; idx < 16 * 57; idx += 256) {        // conv3
        int oc = idx / 57, t = idx % 57;
        float s = b3c[oc];
        for (int ic = 0; ic < 16; ++ic) {
            const float* xr = &Z2[ic * 121];
            const float* wr = &w3c[(oc * 16 + ic) * 10];
            #pragma unroll
            for (int k = 0; k < 10; ++k) {
                int p = 2 * t + k - 1;
                if (p >= 0 && p < 120) s += xr[p] * wr[k];
            }
        }
        Z3[oc * 58 + t] = s >= 0.f ? s : 0.01f * s;
    }
    __syncthreads();
    if (tid < 80) {                                          // maxpool k=10 s=10
        int ch = tid / 5, wd = tid % 5;
        const float* p = &Z3[ch * 58 + wd * 10];
        float m = p[0];
        #pragma unroll
        for (int k = 1; k < 10; ++k) m = fmaxf(m, p[k]);
        ZF[tid] = m;
    }
    __syncthreads();
    const HeadW hws[3] = {hw0, hw1, hw2};
    #pragma unroll
    for (int hd = 0; hd < 3; ++hd) {
        if (tid < 128) {
            float s = hws[hd].b1[tid];
            for (int k = 0; k < 80; ++k) s += ZF[k] * hws[hd].w1[tid * 80 + k];
            HB[tid] = s >= 0.f ? s : 0.01f * s;
        }
        __syncthreads();
        if (tid < 128) {
            float s = hws[hd].b2[tid];
            for (int k = 0; k < 128; ++k) s += HB[k] * hws[hd].w2[tid * 128 + k];
            HC[tid] = s >= 0.f ? s : 0.01f * s;
        }
        __syncthreads();
        if (tid == 0) {
            float o = hws[hd].b3[0];
            for (int k = 0; k < 128; ++k) o += HC[k] * hws[hd].w3[k];
            out[g * 3 + hd] = (hd == 0) ? tanhf(o) : o;
        }
        __syncthreads();
    }
}

extern "C" void kernel_launch(void* const* d_in, const int* in_sizes, int n_in,
                              void* d_out, int out_size, void* d_ws, size_t ws_size,
                              hipStream_t stream) {
    const float* x     = (const float*)d_in[0];
    const float* ea    = (const float*)d_in[1];
    const float* g1_W  = (const float*)d_in[2];
    const float* g1_We = (const float*)d_in[3];
    const float* g1_as = (const float*)d_in[4];
    const float* g1_ad = (const float*)d_in[5];
    const float* g1_ae = (const float*)d_in[6];
    const float* g1_b  = (const float*)d_in[7];
    const float* g2_W  = (const float*)d_in[8];
    const float* g2_We = (const float*)d_in[9];
    const float* g2_as = (const float*)d_in[10];
    const float* g2_ad = (const float*)d_in[11];
    const float* g2_ae = (const float*)d_in[12];
    const float* g2_b  = (const float*)d_in[13];
    const float* c1w = (const float*)d_in[14]; const float* c1b = (const float*)d_in[15];
    const float* c2w = (const float*)d_in[16]; const float* c2b = (const float*)d_in[17];
    const float* c3w = (const float*)d_in[18]; const float* c3b = (const float*)d_in[19];
    const int*   eidx = (const int*)d_in[38];
    float* out = (float*)d_out;

    const int N = in_sizes[0] / 5;
    const int E = in_sizes[38] / 2;
    const int B = out_size / 3, SIZE = 500;
    const int* src = eidx;
    const int* dst = eidx + E;

    // ---- workspace layout (float units, each offset rounded to 4) ----
    float* ws = (float*)d_ws;
    size_t o = 0;
    auto alloc = [&](size_t n) { float* p = ws + o; o = (o + n + 3) & ~(size_t)3; return p; };
    float*    A     = alloc((size_t)N * 80);          // xp dense
    float*    Hbuf  = alloc((size_t)N * 80);          // h1 then h2
    float*    sterm = alloc((size_t)N * 16);
    float*    dterm = alloc((size_t)N * 16);
    int*      off   = (int*)alloc((size_t)N + 1);
    int*      cur   = (int*)alloc((size_t)N);
    int*      bsum  = (int*)alloc(512);
    int*      esrc  = (int*)alloc((size_t)E);
    float2*   eea   = (float2*)alloc((size_t)E * 2);
    unsigned* pool  = (unsigned*)alloc((size_t)B * SIZE * 80);
    float*    c1    = alloc((size_t)B * 16 * 247);

    const int BS = 256;
    auto blocks = [&](long long n) { return (int)((n + BS - 1) / BS); };
    const int G = (N + SCAN_B - 1) / SCAN_B;          // <= 512 for N <= 131072

    // ================= CSR build (shared by both layers) =================
    hipMemsetAsync(cur, 0, (size_t)N * 4, stream);
    k_hist<<<blocks(E), BS, 0, stream>>>(dst, cur, E);
    k_bsum<<<G, SCAN_B, 0, stream>>>(cur, bsum, N);
    k_bscan<<<1, 512, 0, stream>>>(bsum, G);
    k_apply<<<G, SCAN_B, 0, stream>>>(cur, off, cur, bsum, N);
    k_scatter<<<blocks(E), BS, 0, stream>>>(src, dst, ea, cur, esrc, eea, E);

    // ================= GAT layer 1 =================
    k_proj5t<<<blocks((long long)N * 16), BS, 0, stream>>>(x, g1_W, g1_as, g1_ad,
                                                           A, sterm, dterm, N);
    k_gat<false><<<blocks((long long)N * 16), BS, 0, stream>>>(
        off, esrc, eea, sterm, dterm, g1_We, g1_ae, A, g1_b, Hbuf, N);

    // ================= GAT layer 2 =================
    k_proj80t<<<(N + 127) / 128, 256, 0, stream>>>(Hbuf, g2_W, g2_as, g2_ad,
                                                   A, sterm, dterm, N);
    k_gat<true><<<blocks((long long)N * 16), BS, 0, stream>>>(
        off, esrc, eea, sterm, dterm, g2_We, g2_ae, A, g2_b, Hbuf, N);

    // ================= pooling (encoded; decode fused into conv1) =================
    hipMemsetAsync(pool, 0, (size_t)B * SIZE * 80 * 4, stream);
    k_pool<<<blocks((long long)N * 80), BS, 0, stream>>>(x, Hbuf, pool, N);

    // ================= conv tower + heads =================
    k_conv1<<<B * 4, 256, 0, stream>>>(pool, c1w, c1b, c1);
    HeadW h0 = {(const float*)d_in[20], (const float*)d_in[21], (const float*)d_in[22],
                (const float*)d_in[23], (const float*)d_in[24], (const float*)d_in[25]};
    HeadW h1 = {(const float*)d_in[26], (const float*)d_in[27], (const float*)d_in[28],
                (const float*)d_in[29], (const float*)d_in[30], (const float*)d_in[31]};
    HeadW h2 = {(const float*)d_in[32], (const float*)d_in[33], (const float*)d_in[34],
                (const float*)d_in[35], (const float*)d_in[36], (const float*)d_in[37]};
    k_tail<<<B, 256, 0, stream>>>(c1, c2w, c2b, c3w, c3b, h0, h1, h2, out);
}